// Round 2
// baseline (179.974 us; speedup 1.0000x reference)
//
#include <hip/hip_runtime.h>
#include <math.h>

// DMP rollout: DIM=1024, NB=25, T=10001 rows of [y0 | y | dy] (3*1024 fp32).
// Strategy: the per-step update is affine in (y,dy) with CONSTANT linear part A.
//   dy' = dy + dt*(25*(6.25*(g-y) - dy) + f(t))
//   y'  = y  + dt*dy'
// f_d(t) = (w_d . q_t) * (g_d - y0_d), q_t = 1000 * x_t * psi_t / sum(psi_t),
// x_t = 0.999^t (closed form). => chunk-parallel linear scan (3-phase):
//   k_tables: q table [10000][32]
//   phase1:   per (chunk,dim) run L steps from zero state -> affine offset r_c
//   phase2:   per dim, serial scan over C chunks with A^L (double) -> vstart
//   phase3:   replay each chunk from correct start, stream 123 MB of output.

#define DIM    1024
#define NB     25
#define NSTEP  10000
#define CHUNKS 100
#define LSTEPS 100
#define QS     32   // padded row stride for q table

__global__ void k_tables(float* __restrict__ q) {
    int t0 = blockIdx.x * blockDim.x + threadIdx.x;
    if (t0 >= NSTEP) return;
    int t = t0 + 1;                       // step i uses x after decay: x_t = decay^t
    const float decay = 1.0f - 1.0f * 1.0f * 0.001f;   // 1 - ALPHA_X*TAU*DT
    float x = (float)exp((double)t * log((double)decay));
    float psi[NB];
    float S = 0.f;
#pragma unroll
    for (int k = 0; k < NB; ++k) {
        float lk = (10.0f / 24.0f) * (float)k;   // linspace(0, 10, 25)
        float ck = expf(-lk);                     // ALPHA_X = 1
        float hk = 25.0f / ck;                    // NB / c
        float dxc = x - ck;
        float p = expf(-hk * dxc * dxc);
        psi[k] = p;
        S += p;
    }
    float scale = 1000.0f * x / S;                // WEIGHT_SCALE * x / sum(psi)
#pragma unroll
    for (int k = 0; k < NB; ++k) q[t0 * QS + k] = psi[k] * scale;
#pragma unroll
    for (int k = NB; k < QS; ++k) q[t0 * QS + k] = 0.f;
}

__global__ __launch_bounds__(256) void k_phase1(const float* __restrict__ q,
                                                const float* __restrict__ W,
                                                const float* __restrict__ g,
                                                const float* __restrict__ y0,
                                                float* __restrict__ r) {
    const int c = blockIdx.y;
    const int d = blockIdx.x * 256 + threadIdx.x;
    float w[NB];
#pragma unroll
    for (int k = 0; k < NB; ++k) w[k] = W[d * NB + k];
    const float gd  = g[d];
    const float gd0 = gd - y0[d];
    float y = 0.f, dy = 0.f;                      // zero init -> affine offset
    const float* qp = q + (size_t)c * LSTEPS * QS;
#pragma unroll 4
    for (int j = 0; j < LSTEPS; ++j) {
        float dot = 0.f;
#pragma unroll
        for (int k = 0; k < NB; ++k) dot += w[k] * qp[k];   // qp wave-uniform
        qp += QS;
        float f   = dot * gd0;
        float ddy = 25.0f * (6.25f * (gd - y) - dy) + f;
        dy = dy + 0.001f * ddy;
        y  = y + 0.001f * dy;
    }
    r[c * DIM + d] = y;
    r[CHUNKS * DIM + c * DIM + d] = dy;
}

__global__ void k_phase2(const float* __restrict__ r,
                         const float* __restrict__ y0,
                         float* __restrict__ vs,
                         double m00, double m01, double m10, double m11) {
    const int d = blockIdx.x * blockDim.x + threadIdx.x;   // 1024 threads
    double vy = (double)y0[d], vdy = 0.0;
    float ry = r[d], rdy = r[CHUNKS * DIM + d];
    for (int c = 0; c < CHUNKS; ++c) {
        vs[c * DIM + d] = (float)vy;
        vs[CHUNKS * DIM + c * DIM + d] = (float)vdy;
        float ry_n = 0.f, rdy_n = 0.f;
        if (c + 1 < CHUNKS) {                      // prefetch next chunk's offset
            ry_n  = r[(c + 1) * DIM + d];
            rdy_n = r[(CHUNKS + c + 1) * DIM + d];
        }
        double ny  = m00 * vy + m01 * vdy + (double)ry;
        double ndy = m10 * vy + m11 * vdy + (double)rdy;
        vy = ny; vdy = ndy;
        ry = ry_n; rdy = rdy_n;
    }
}

__global__ __launch_bounds__(256) void k_phase3(const float* __restrict__ q,
                                                const float* __restrict__ W,
                                                const float* __restrict__ g,
                                                const float* __restrict__ y0,
                                                const float* __restrict__ vs,
                                                float* __restrict__ out) {
    const int c = blockIdx.y;
    const int d = blockIdx.x * 256 + threadIdx.x;
    float w[NB];
#pragma unroll
    for (int k = 0; k < NB; ++k) w[k] = W[d * NB + k];
    const float y0d = y0[d];
    const float gd  = g[d];
    const float gd0 = gd - y0d;
    float y  = vs[c * DIM + d];
    float dy = vs[CHUNKS * DIM + c * DIM + d];
    if (c == 0) {                                  // row 0: [y0 | y0 | 0]
        out[d] = y0d;
        out[DIM + d] = y0d;
        out[2 * DIM + d] = 0.f;
    }
    const float* qp = q + (size_t)c * LSTEPS * QS;
    float* op = out + (size_t)(c * LSTEPS + 1) * (3 * DIM);
#pragma unroll 4
    for (int j = 0; j < LSTEPS; ++j) {
        float dot = 0.f;
#pragma unroll
        for (int k = 0; k < NB; ++k) dot += w[k] * qp[k];
        qp += QS;
        float f   = dot * gd0;
        float ddy = 25.0f * (6.25f * (gd - y) - dy) + f;
        dy = dy + 0.001f * ddy;
        y  = y + 0.001f * dy;
        op[d] = y0d;
        op[DIM + d] = y;
        op[2 * DIM + d] = dy;
        op += 3 * DIM;
    }
}

extern "C" void kernel_launch(void* const* d_in, const int* in_sizes, int n_in,
                              void* d_out, int out_size, void* d_ws, size_t ws_size,
                              hipStream_t stream) {
    const float* y0 = (const float*)d_in[0];
    const float* g  = (const float*)d_in[1];
    const float* W  = (const float*)d_in[2];
    float* out = (float*)d_out;

    float* q  = (float*)d_ws;                       // [NSTEP][QS]      1.28 MB
    float* r  = q  + (size_t)NSTEP * QS;            // [2][CHUNKS][DIM] 0.8 MB
    float* vs = r  + (size_t)2 * CHUNKS * DIM;      // [2][CHUNKS][DIM] 0.8 MB

    // A^LSTEPS in double (host, deterministic, same every call).
    const double dtD = (double)0.001f;              // match fp32 constant
    const double aD = 25.0, bD = 6.25;
    const double a00 = 1.0 - dtD * dtD * aD * bD;
    const double a01 = dtD * (1.0 - dtD * aD);
    const double a10 = -dtD * aD * bD;
    const double a11 = 1.0 - dtD * aD;
    double m00 = 1, m01 = 0, m10 = 0, m11 = 1;
    for (int i = 0; i < LSTEPS; ++i) {
        double t00 = a00 * m00 + a01 * m10;
        double t01 = a00 * m01 + a01 * m11;
        double t10 = a10 * m00 + a11 * m10;
        double t11 = a10 * m01 + a11 * m11;
        m00 = t00; m01 = t01; m10 = t10; m11 = t11;
    }

    k_tables<<<(NSTEP + 255) / 256, 256, 0, stream>>>(q);
    k_phase1<<<dim3(DIM / 256, CHUNKS), 256, 0, stream>>>(q, W, g, y0, r);
    k_phase2<<<DIM / 256, 256, 0, stream>>>(r, y0, vs, m00, m01, m10, m11);
    k_phase3<<<dim3(DIM / 256, CHUNKS), 256, 0, stream>>>(q, W, g, y0, vs, out);
}

// Round 3
// 163.496 us; speedup vs baseline: 1.1008x; 1.1008x over previous
//
#include <hip/hip_runtime.h>
#include <math.h>

// DMP rollout: DIM=1024, NB=25, T=10001 rows of [y0 | y | dy] (3*1024 fp32).
// v=(y,dy) evolves affinely: v' = A v + u(t), A constant (dt,25,6.25 const),
// u(t) = (dt^2,dt)*e(t), e(t) = 156.25*g + (w.q_t)*(g-y0),
// q_t = 1000*x_t*psi_t/sum(psi_t), x_t = 0.999^t closed-form.
// 4 kernels:
//  k_prep: per chunk c (200 chunks x 50 steps): q rows + coefficient vectors
//          Q_c[k] = sum_j p_j * q_{c,j}[k], p_j = A^(L-1-j)(dt^2,dt)^T (f64).
//  k_dots: per (c,d): chunk offset r_c = 156.25*sp*g + (g-y0)*(w.Q_c)  [in d_out scratch]
//  k_scan: per d: serial f64 scan over 200 chunks with A^L -> chunk start states
//  k_roll: replay each chunk (exact fp32 steps), stream 123 MB of output.

#define DIM    1024
#define NB     25
#define NSTEP  10000
#define CHUNKS 200
#define LSTEPS 50
#define QS     32   // padded row stride for q / coef tables

__global__ __launch_bounds__(64) void k_prep(float* __restrict__ q,
                                             float* __restrict__ QY,
                                             float* __restrict__ QD,
                                             double logdecay,
                                             double a00, double a01,
                                             double a10, double a11) {
    __shared__ float lq[LSTEPS][NB + 1];
    const int c = blockIdx.x;
    const int tid = threadIdx.x;
    if (tid < LSTEPS) {
        int t = c * LSTEPS + tid + 1;            // x after decay at step t
        float x = (float)exp((double)t * logdecay);
        float psi[NB];
        float S = 0.f;
#pragma unroll
        for (int k = 0; k < NB; ++k) {
            float lk = (10.0f / 24.0f) * (float)k;   // linspace(0,10,25)
            float ck = expf(-lk);
            float hk = 25.0f / ck;
            float dxc = x - ck;
            float p = expf(-hk * dxc * dxc);
            psi[k] = p;
            S += p;
        }
        float scale = 1000.0f * x / S;
        float* qrow = q + (size_t)(c * LSTEPS + tid) * QS;
#pragma unroll
        for (int k = 0; k < NB; ++k) {
            float v = psi[k] * scale;
            qrow[k] = v;
            lq[tid][k] = v;
        }
    }
    __syncthreads();
    if (tid < NB) {
        // p_j = A^(L-1-j) (dt^2, dt)^T, accumulated backward in f64.
        double py = (double)0.001f * (double)0.001f;
        double pd = (double)0.001f;
        double qy = 0.0, qd = 0.0;
        for (int j = LSTEPS - 1; j >= 0; --j) {
            double v = (double)lq[j][tid];
            qy += py * v;
            qd += pd * v;
            double npy = a00 * py + a01 * pd;
            double npd = a10 * py + a11 * pd;
            py = npy; pd = npd;
        }
        QY[c * QS + tid] = (float)qy;
        QD[c * QS + tid] = (float)qd;
    }
}

__global__ __launch_bounds__(256) void k_dots(const float* __restrict__ QY,
                                              const float* __restrict__ QD,
                                              const float* __restrict__ W,
                                              const float* __restrict__ g,
                                              const float* __restrict__ y0,
                                              float* __restrict__ dots,
                                              double spY, double spD) {
    const int c = blockIdx.y;
    const int d = blockIdx.x * 256 + threadIdx.x;
    const float gd  = g[d];
    const float gd0 = gd - y0[d];
    float sy = 0.f, sd = 0.f;
#pragma unroll
    for (int k = 0; k < NB; ++k) {
        float wk = W[d * NB + k];
        sy += wk * QY[c * QS + k];     // QY wave-uniform -> scalarizable
        sd += wk * QD[c * QS + k];
    }
    dots[c * DIM + d]                = (float)((double)gd * spY + (double)gd0 * (double)sy);
    dots[CHUNKS * DIM + c * DIM + d] = (float)((double)gd * spD + (double)gd0 * (double)sd);
}

__global__ __launch_bounds__(64) void k_scan(const float* __restrict__ dots,
                                             const float* __restrict__ y0,
                                             float* __restrict__ vs,
                                             double m00, double m01,
                                             double m10, double m11) {
    __shared__ float ls[CHUNKS][2][64];           // 102.4 KB
    const int tid = threadIdx.x;
    const int d = blockIdx.x * 64 + tid;
    // stage all per-dim chunk offsets into LDS (pipelined coalesced loads)
    for (int c = 0; c < CHUNKS; ++c) {
        ls[c][0][tid] = dots[c * DIM + d];
        ls[c][1][tid] = dots[CHUNKS * DIM + c * DIM + d];
    }
    double vy = (double)y0[d], vdy = 0.0;
    for (int c = 0; c < CHUNKS; ++c) {
        vs[c * DIM + d] = (float)vy;
        vs[CHUNKS * DIM + c * DIM + d] = (float)vdy;
        double ny  = m00 * vy + m01 * vdy + (double)ls[c][0][tid];
        double ndy = m10 * vy + m11 * vdy + (double)ls[c][1][tid];
        vy = ny; vdy = ndy;
    }
}

__global__ __launch_bounds__(64) void k_roll(const float* __restrict__ q,
                                             const float* __restrict__ W,
                                             const float* __restrict__ g,
                                             const float* __restrict__ y0,
                                             const float* __restrict__ vs,
                                             float* __restrict__ out) {
    const int c = blockIdx.y;
    const int d = blockIdx.x * 64 + threadIdx.x;
    float w[NB];
#pragma unroll
    for (int k = 0; k < NB; ++k) w[k] = W[d * NB + k];
    const float y0d = y0[d];
    const float gd  = g[d];
    const float gd0 = gd - y0d;
    float y  = vs[c * DIM + d];
    float dy = vs[CHUNKS * DIM + c * DIM + d];
    if (c == 0) {                                  // row 0: [y0 | y0 | 0]
        out[d] = y0d;
        out[DIM + d] = y0d;
        out[2 * DIM + d] = 0.f;
    }
    const float* qp = q + (size_t)c * LSTEPS * QS;
    float* op = out + (size_t)(c * LSTEPS + 1) * (3 * DIM);
#pragma unroll 2
    for (int j = 0; j < LSTEPS; ++j) {
        float dot = 0.f;
#pragma unroll
        for (int k = 0; k < NB; ++k) dot += w[k] * qp[k];   // qp wave-uniform
        qp += QS;
        float f   = dot * gd0;
        float ddy = 25.0f * (6.25f * (gd - y) - dy) + f;
        dy = dy + 0.001f * ddy;
        y  = y + 0.001f * dy;
        op[d] = y0d;
        op[DIM + d] = y;
        op[2 * DIM + d] = dy;
        op += 3 * DIM;
    }
}

extern "C" void kernel_launch(void* const* d_in, const int* in_sizes, int n_in,
                              void* d_out, int out_size, void* d_ws, size_t ws_size,
                              hipStream_t stream) {
    const float* y0 = (const float*)d_in[0];
    const float* g  = (const float*)d_in[1];
    const float* W  = (const float*)d_in[2];
    float* out = (float*)d_out;

    float* q  = (float*)d_ws;                        // [NSTEP][QS]        1.28 MB
    float* QY = q  + (size_t)NSTEP * QS;             // [CHUNKS][QS]       25.6 KB
    float* QD = QY + (size_t)CHUNKS * QS;            // [CHUNKS][QS]       25.6 KB
    float* vs = QD + (size_t)CHUNKS * QS;            // [2][CHUNKS][DIM]   1.6 MB
    float* dots = out;                               // scratch in d_out (overwritten by k_roll)

    // Step matrix A (f64, dt as the fp32-rounded constant), A^LSTEPS, and
    // sp = 156.25 * sum_j p_j  with p_j = A^(L-1-j)(dt^2,dt)^T.
    const double dtD = (double)0.001f;
    const double aD = 25.0, abD = 25.0 * 6.25;
    const double a00 = 1.0 - dtD * dtD * abD;
    const double a01 = dtD * (1.0 - dtD * aD);
    const double a10 = -dtD * abD;
    const double a11 = 1.0 - dtD * aD;
    double m00 = 1, m01 = 0, m10 = 0, m11 = 1;
    double py = dtD * dtD, pd = dtD, sY = 0.0, sD = 0.0;
    for (int i = 0; i < LSTEPS; ++i) {
        double t00 = a00 * m00 + a01 * m10;
        double t01 = a00 * m01 + a01 * m11;
        double t10 = a10 * m00 + a11 * m10;
        double t11 = a10 * m01 + a11 * m11;
        m00 = t00; m01 = t01; m10 = t10; m11 = t11;
        sY += py; sD += pd;
        double npy = a00 * py + a01 * pd;
        double npd = a10 * py + a11 * pd;
        py = npy; pd = npd;
    }
    const double spY = 156.25 * sY;
    const double spD = 156.25 * sD;
    const double logdecay = log((double)(1.0f - 0.001f));

    k_prep<<<CHUNKS, 64, 0, stream>>>(q, QY, QD, logdecay, a00, a01, a10, a11);
    k_dots<<<dim3(DIM / 256, CHUNKS), 256, 0, stream>>>(QY, QD, W, g, y0, dots, spY, spD);
    k_scan<<<DIM / 64, 64, 0, stream>>>(dots, y0, vs, m00, m01, m10, m11);
    k_roll<<<dim3(DIM / 64, CHUNKS), 64, 0, stream>>>(q, W, g, y0, vs, out);
}

// Round 10
// 152.828 us; speedup vs baseline: 1.1776x; 1.0698x over previous
//
#include <hip/hip_runtime.h>
#include <math.h>

// DMP rollout: DIM=1024, NB=25, T=10001 rows of [y0 | y | dy] (3*1024 fp32).
// v=(y,dy) affine recurrence with constant 2x2 A; forcing u_t = (dt^2,dt)*e_t,
// e_t = 156.25*g + (w.q_t)*(g-y0), q_t closed-form in t.
// Pipeline (6 small kernels, all on stream):
//  k_prep : q table rows + per-chunk coef vectors QY/QD (f64 backward scan)
//           + W transpose into WT[NB][DIM] (extra blocks).
//  k_dots : per (c,d) chunk offset r_c (coalesced WT loads).   [dots in d_out scratch]
//  k_scanA: 2-level scan, level-1 zero-init partials per superchunk (f64).
//  k_scanB: level-2 serial scan over 25 superchunks (f64).
//  k_scanC: recover all 250 chunk start states (f64).
//  k_roll : replay each chunk exactly in fp32; q slice staged in LDS
//           (broadcast b128 reads), coalesced stores; 123 MB stream.

#define DIM    1024
#define NB     25
#define NSTEP  10000
#define CHUNKS 250
#define LSTEPS 40
#define SC     25     // superchunks
#define SS     10     // chunks per superchunk
#define QS     32     // padded q row stride (floats)

__global__ __launch_bounds__(64) void k_prep(float* __restrict__ q,
                                             float* __restrict__ QY,
                                             float* __restrict__ QD,
                                             float* __restrict__ WT,
                                             const float* __restrict__ W,
                                             double logdecay,
                                             double a00, double a01,
                                             double a10, double a11) {
    const int c = blockIdx.x;
    const int tid = threadIdx.x;
    if (c >= CHUNKS) {                       // W transpose blocks
        int k = c - CHUNKS;                  // 0..24
        for (int d = tid; d < DIM; d += 64)
            WT[k * DIM + d] = W[d * NB + k];
        return;
    }
    __shared__ float lq[LSTEPS][NB + 1];
    if (tid < LSTEPS) {
        int t = c * LSTEPS + tid + 1;        // x after decay at step t
        float x = (float)exp((double)t * logdecay);
        float psi[NB];
        float S = 0.f;
#pragma unroll
        for (int k = 0; k < NB; ++k) {
            float lk = (10.0f / 24.0f) * (float)k;   // linspace(0,10,25)
            float ck = expf(-lk);
            float hk = 25.0f / ck;
            float dxc = x - ck;
            float p = expf(-hk * dxc * dxc);
            psi[k] = p;
            S += p;
        }
        float scale = 1000.0f * x / S;
        float* qrow = q + (size_t)(c * LSTEPS + tid) * QS;
#pragma unroll
        for (int k = 0; k < NB; ++k) {
            float v = psi[k] * scale;
            qrow[k] = v;
            lq[tid][k] = v;
        }
    }
    __syncthreads();
    if (tid < NB) {
        // p_j = A^(L-1-j) (dt^2, dt)^T accumulated backward in f64
        double py = (double)0.001f * (double)0.001f;
        double pd = (double)0.001f;
        double qy = 0.0, qd = 0.0;
        for (int j = LSTEPS - 1; j >= 0; --j) {
            double v = (double)lq[j][tid];
            qy += py * v;
            qd += pd * v;
            double npy = a00 * py + a01 * pd;
            double npd = a10 * py + a11 * pd;
            py = npy; pd = npd;
        }
        QY[c * QS + tid] = (float)qy;
        QD[c * QS + tid] = (float)qd;
    }
}

__global__ __launch_bounds__(256) void k_dots(const float* __restrict__ QY,
                                              const float* __restrict__ QD,
                                              const float* __restrict__ WT,
                                              const float* __restrict__ g,
                                              const float* __restrict__ y0,
                                              float* __restrict__ dots,
                                              double spY, double spD) {
    const int idx = blockIdx.x * 256 + threadIdx.x;   // DIM*CHUNKS threads
    const int d = idx & (DIM - 1);
    const int c = idx >> 10;
    const float gd  = g[d];
    const float gd0 = gd - y0[d];
    float sy = 0.f, sd = 0.f;
#pragma unroll
    for (int k = 0; k < NB; ++k) {
        float wk = WT[k * DIM + d];          // coalesced
        sy += wk * QY[c * QS + k];           // wave-uniform
        sd += wk * QD[c * QS + k];
    }
    dots[c * DIM + d]                = (float)((double)gd * spY + (double)gd0 * (double)sy);
    dots[CHUNKS * DIM + c * DIM + d] = (float)((double)gd * spD + (double)gd0 * (double)sd);
}

// level-1: per (superchunk, dim) zero-init partial over its SS chunks
__global__ __launch_bounds__(256) void k_scanA(const float* __restrict__ dots,
                                               float* __restrict__ usY,
                                               float* __restrict__ usD,
                                               double m00, double m01,
                                               double m10, double m11) {
    const int idx = blockIdx.x * 256 + threadIdx.x;   // DIM*SC threads
    const int d = idx & (DIM - 1);
    const int s = idx >> 10;
    double vy = 0.0, vdy = 0.0;
#pragma unroll
    for (int i = 0; i < SS; ++i) {
        int c = s * SS + i;
        double ry = (double)dots[c * DIM + d];
        double rd = (double)dots[CHUNKS * DIM + c * DIM + d];
        double ny  = m00 * vy + m01 * vdy + ry;
        double ndy = m10 * vy + m11 * vdy + rd;
        vy = ny; vdy = ndy;
    }
    usY[s * DIM + d] = (float)vy;
    usD[s * DIM + d] = (float)vdy;
}

// level-2: per dim serial scan over SC superchunks
__global__ __launch_bounds__(256) void k_scanB(const float* __restrict__ usY,
                                               const float* __restrict__ usD,
                                               const float* __restrict__ y0,
                                               float* __restrict__ ssY,
                                               float* __restrict__ ssD,
                                               double b00, double b01,
                                               double b10, double b11) {
    const int d = blockIdx.x * 256 + threadIdx.x;     // DIM threads
    float uy[SC], ud[SC];
#pragma unroll
    for (int s = 0; s < SC; ++s) {
        uy[s] = usY[s * DIM + d];
        ud[s] = usD[s * DIM + d];
    }
    double vy = (double)y0[d], vdy = 0.0;
#pragma unroll
    for (int s = 0; s < SC; ++s) {
        ssY[s * DIM + d] = (float)vy;
        ssD[s * DIM + d] = (float)vdy;
        double ny  = b00 * vy + b01 * vdy + (double)uy[s];
        double ndy = b10 * vy + b11 * vdy + (double)ud[s];
        vy = ny; vdy = ndy;
    }
}

// level-3: recover every chunk's start state
__global__ __launch_bounds__(256) void k_scanC(const float* __restrict__ dots,
                                               const float* __restrict__ ssY,
                                               const float* __restrict__ ssD,
                                               float* __restrict__ vs,
                                               double m00, double m01,
                                               double m10, double m11) {
    const int idx = blockIdx.x * 256 + threadIdx.x;
    const int d = idx & (DIM - 1);
    const int s = idx >> 10;
    double vy = (double)ssY[s * DIM + d];
    double vdy = (double)ssD[s * DIM + d];
#pragma unroll
    for (int i = 0; i < SS; ++i) {
        int c = s * SS + i;
        vs[c * DIM + d] = (float)vy;
        vs[CHUNKS * DIM + c * DIM + d] = (float)vdy;
        double ry = (double)dots[c * DIM + d];
        double rd = (double)dots[CHUNKS * DIM + c * DIM + d];
        double ny  = m00 * vy + m01 * vdy + ry;
        double ndy = m10 * vy + m11 * vdy + rd;
        vy = ny; vdy = ndy;
    }
}

__global__ __launch_bounds__(256) void k_roll(const float* __restrict__ q,
                                              const float* __restrict__ WT,
                                              const float* __restrict__ g,
                                              const float* __restrict__ y0,
                                              const float* __restrict__ vs,
                                              float* __restrict__ out) {
    __shared__ float lq[LSTEPS][QS];                   // 5.12 KB
    const int c = blockIdx.y;
    const int tid = threadIdx.x;
    const int d = blockIdx.x * 256 + tid;
    {   // stage this chunk's q slice (320 float4)
        const float4* src = (const float4*)(q + (size_t)c * LSTEPS * QS);
        float4* dst = (float4*)&lq[0][0];
        for (int i = tid; i < LSTEPS * (QS / 4); i += 256) dst[i] = src[i];
    }
    float w[NB];
#pragma unroll
    for (int k = 0; k < NB; ++k) w[k] = WT[k * DIM + d];   // coalesced
    const float y0d = y0[d];
    const float gd  = g[d];
    const float gd0 = gd - y0d;
    float y  = vs[c * DIM + d];
    float dy = vs[CHUNKS * DIM + c * DIM + d];
    __syncthreads();
    if (c == 0) {                                      // row 0: [y0 | y0 | 0]
        out[d] = y0d;
        out[DIM + d] = y0d;
        out[2 * DIM + d] = 0.f;
    }
    float* op = out + (size_t)(c * LSTEPS + 1) * (3 * DIM);
#pragma unroll 2
    for (int j = 0; j < LSTEPS; ++j) {
        const float4* row = (const float4*)&lq[j][0];  // broadcast reads
        float dot = 0.f;
#pragma unroll
        for (int m = 0; m < 6; ++m) {
            float4 qv = row[m];
            dot += w[4 * m + 0] * qv.x;
            dot += w[4 * m + 1] * qv.y;
            dot += w[4 * m + 2] * qv.z;
            dot += w[4 * m + 3] * qv.w;
        }
        dot += w[24] * lq[j][24];
        float f   = dot * gd0;
        float ddy = 25.0f * (6.25f * (gd - y) - dy) + f;
        dy = dy + 0.001f * ddy;
        y  = y + 0.001f * dy;
        op[d] = y0d;
        op[DIM + d] = y;
        op[2 * DIM + d] = dy;
        op += 3 * DIM;
    }
}

extern "C" void kernel_launch(void* const* d_in, const int* in_sizes, int n_in,
                              void* d_out, int out_size, void* d_ws, size_t ws_size,
                              hipStream_t stream) {
    const float* y0 = (const float*)d_in[0];
    const float* g  = (const float*)d_in[1];
    const float* W  = (const float*)d_in[2];
    float* out = (float*)d_out;

    float* q   = (float*)d_ws;                        // [NSTEP][QS]      1.28 MB
    float* QY  = q   + (size_t)NSTEP * QS;            // [CHUNKS][QS]
    float* QD  = QY  + (size_t)CHUNKS * QS;
    float* WT  = QD  + (size_t)CHUNKS * QS;           // [NB][DIM]
    float* usY = WT  + (size_t)NB * DIM;              // [SC][DIM]
    float* usD = usY + (size_t)SC * DIM;
    float* ssY = usD + (size_t)SC * DIM;              // [SC][DIM]
    float* ssD = ssY + (size_t)SC * DIM;
    float* vs  = ssD + (size_t)SC * DIM;              // [2][CHUNKS][DIM] 2 MB
    float* dots = out;                                // scratch in d_out (pre-roll)

    // A (f64 with fp32-rounded dt), M = A^L, B = M^SS, sp = 156.25*sum A^i(dt^2,dt)
    const double dtD = (double)0.001f;
    const double aD = 25.0, abD = 25.0 * 6.25;
    const double a00 = 1.0 - dtD * dtD * abD;
    const double a01 = dtD * (1.0 - dtD * aD);
    const double a10 = -dtD * abD;
    const double a11 = 1.0 - dtD * aD;
    double m00 = 1, m01 = 0, m10 = 0, m11 = 1;
    double py = dtD * dtD, pd = dtD, sY = 0.0, sD = 0.0;
    for (int i = 0; i < LSTEPS; ++i) {
        double t00 = a00 * m00 + a01 * m10;
        double t01 = a00 * m01 + a01 * m11;
        double t10 = a10 * m00 + a11 * m10;
        double t11 = a10 * m01 + a11 * m11;
        m00 = t00; m01 = t01; m10 = t10; m11 = t11;
        sY += py; sD += pd;
        double npy = a00 * py + a01 * pd;
        double npd = a10 * py + a11 * pd;
        py = npy; pd = npd;
    }
    double b00 = 1, b01 = 0, b10 = 0, b11 = 1;        // M^SS
    for (int i = 0; i < SS; ++i) {
        double t00 = m00 * b00 + m01 * b10;
        double t01 = m00 * b01 + m01 * b11;
        double t10 = m10 * b00 + m11 * b10;
        double t11 = m10 * b01 + m11 * b11;
        b00 = t00; b01 = t01; b10 = t10; b11 = t11;
    }
    const double spY = 156.25 * sY;
    const double spD = 156.25 * sD;
    const double logdecay = log((double)(1.0f - 0.001f));

    k_prep<<<CHUNKS + NB, 64, 0, stream>>>(q, QY, QD, WT, W, logdecay, a00, a01, a10, a11);
    k_dots<<<(DIM * CHUNKS) / 256, 256, 0, stream>>>(QY, QD, WT, g, y0, dots, spY, spD);
    k_scanA<<<(DIM * SC) / 256, 256, 0, stream>>>(dots, usY, usD, m00, m01, m10, m11);
    k_scanB<<<DIM / 256, 256, 0, stream>>>(usY, usD, y0, ssY, ssD, b00, b01, b10, b11);
    k_scanC<<<(DIM * SC) / 256, 256, 0, stream>>>(dots, ssY, ssD, vs, m00, m01, m10, m11);
    k_roll<<<dim3(DIM / 256, CHUNKS), 256, 0, stream>>>(q, WT, g, y0, vs, out);
}